// Round 2
// baseline (16323.958 us; speedup 1.0000x reference)
//
#include <hip/hip_runtime.h>
#include <hip/hip_bf16.h>
#include <math.h>

// ---------------- problem constants ----------------
#define BATCH 32
#define DMODEL 768
#define NHEAD 12
#define DHEAD 64
#define DEPTH 12
#define WARM 2
#define KSEL 64
#define MLPD 3072
#define SELH 128
#define NCLS 10
#define PATCH 16
#define IMG 224
#define NTOK 197          // 196 patches + cls
#define NPATCH 196
#define NRED 65           // 1 + K selected tokens
#define LNEPS 1e-6f

// ---------------- helpers ----------------
__device__ __forceinline__ float gelu_f(float x) {
    return 0.5f * x * (1.0f + erff(x * 0.70710678118654752f));
}

// ---------------- im2col (stride-16 / kernel-16 patches: pure re-index) ----------------
__global__ __launch_bounds__(256) void im2col_k(const float* __restrict__ x, float* __restrict__ out) {
    size_t i = (size_t)blockIdx.x * 256 + threadIdx.x;
    const size_t tot = (size_t)BATCH * NPATCH * DMODEL;
    if (i >= tot) return;
    int k = (int)(i % DMODEL);
    int m = (int)(i / DMODEL);
    int b = m / NPATCH, t = m % NPATCH;
    int py = t / 14, px = t % 14;
    int c = k / 256, r = k % 256;
    int kh = r / 16, kw = r % 16;
    out[i] = x[(((size_t)b * 3 + c) * IMG + py * 16 + kh) * IMG + px * 16 + kw];
}

// ---------------- transpose patch_w [D,768] -> [768,D] ----------------
__global__ __launch_bounds__(256) void transpose_k(const float* __restrict__ w, float* wt) {
    int i = blockIdx.x * 256 + threadIdx.x;
    if (i < DMODEL * DMODEL) {
        int d = i / DMODEL, k = i % DMODEL;
        wt[(size_t)k * DMODEL + d] = w[i];
    }
}

// ---------------- cls row: cls_token + pos_embed[0] ----------------
__global__ __launch_bounds__(256) void cls_k(const float* __restrict__ cls_tok, const float* __restrict__ pos,
                                             float* xtok) {
    int i = blockIdx.x * 256 + threadIdx.x;
    if (i < BATCH * DMODEL) {
        int b = i / DMODEL, d = i % DMODEL;
        xtok[(size_t)b * NTOK * DMODEL + d] = cls_tok[d] + pos[d];
    }
}

// ---------------- LayerNorm: one 256-thread block per row (768 cols) ----------------
__global__ __launch_bounds__(256) void ln_k(const float* __restrict__ in, float* out,
                                            const float* __restrict__ g, const float* __restrict__ b,
                                            size_t rstride) {
    int row = blockIdx.x;
    const float* p = in + (size_t)row * rstride;
    int tid = threadIdx.x;
    float v0 = p[tid], v1 = p[tid + 256], v2 = p[tid + 512];
    float s = v0 + v1 + v2;
    float sq = v0 * v0 + v1 * v1 + v2 * v2;
    for (int off = 32; off; off >>= 1) {
        s += __shfl_xor(s, off);
        sq += __shfl_xor(sq, off);
    }
    __shared__ float red[8];
    int wid = tid >> 6;
    if ((tid & 63) == 0) { red[wid] = s; red[wid + 4] = sq; }
    __syncthreads();
    s = red[0] + red[1] + red[2] + red[3];
    sq = red[4] + red[5] + red[6] + red[7];
    float mean = s * (1.0f / 768.0f);
    float var = sq * (1.0f / 768.0f) - mean * mean;
    float inv = 1.0f / sqrtf(var + LNEPS);
    float* q = out + (size_t)row * DMODEL;
    q[tid]       = (v0 - mean) * inv * g[tid]       + b[tid];
    q[tid + 256] = (v1 - mean) * inv * g[tid + 256] + b[tid + 256];
    q[tid + 512] = (v2 - mean) * inv * g[tid + 512] + b[tid + 512];
}

// ---------------- SGEMM: C[M,N] = A[M,K] @ W[K,N] (+epilogues) ----------------
// 128x128 tile, BK=8, 256 threads, 8x8 per-thread split micro-tile.
#define GBM 128
#define GBN 128
#define GBK 8
constexpr int EPI_BIAS = 1, EPI_GELU = 2, EPI_RESID = 4, EPI_PATCH = 8;

template <int EPI>
__global__ __launch_bounds__(256) void sgemm_k(const float* __restrict__ A, const float* __restrict__ W,
                                               const float* bias, const float* extra, float* C,
                                               int M, int N, int K) {
    __shared__ float As[GBK][GBM];
    __shared__ float Bs[GBK][GBN];
    const int tid = threadIdx.x;
    const int tx = tid & 15;   // col group
    const int ty = tid >> 4;   // row group
    const int row0 = blockIdx.y * GBM;
    const int col0 = blockIdx.x * GBN;

    const int arow = tid >> 1;          // 0..127
    const int acol = (tid & 1) << 2;    // 0 / 4
    const int brow = tid >> 5;          // 0..7
    const int bcol = (tid & 31) << 2;   // 0..124

    const float* Ap = A + (size_t)(row0 + arow) * K + acol;
    const float* Wp = W + (size_t)brow * N + col0 + bcol;
    const bool aok = (row0 + arow) < M;

    float acc[8][8];
#pragma unroll
    for (int i = 0; i < 8; ++i)
#pragma unroll
        for (int j = 0; j < 8; ++j) acc[i][j] = 0.0f;

    const int nk = K / GBK;
    for (int kk = 0; kk < nk; ++kk) {
        float4 av = aok ? *(const float4*)Ap : make_float4(0.f, 0.f, 0.f, 0.f);
        float4 bv = *(const float4*)Wp;
        __syncthreads();
        As[acol + 0][arow] = av.x;
        As[acol + 1][arow] = av.y;
        As[acol + 2][arow] = av.z;
        As[acol + 3][arow] = av.w;
        *(float4*)&Bs[brow][bcol] = bv;
        __syncthreads();
#pragma unroll
        for (int k = 0; k < GBK; ++k) {
            float4 a0 = *(const float4*)&As[k][ty * 4];
            float4 a1 = *(const float4*)&As[k][64 + ty * 4];
            float4 b0 = *(const float4*)&Bs[k][tx * 4];
            float4 b1 = *(const float4*)&Bs[k][64 + tx * 4];
            float ar[8] = {a0.x, a0.y, a0.z, a0.w, a1.x, a1.y, a1.z, a1.w};
            float br[8] = {b0.x, b0.y, b0.z, b0.w, b1.x, b1.y, b1.z, b1.w};
#pragma unroll
            for (int i = 0; i < 8; ++i)
#pragma unroll
                for (int j = 0; j < 8; ++j) acc[i][j] = fmaf(ar[i], br[j], acc[i][j]);
        }
        Ap += GBK;
        Wp += (size_t)GBK * N;
    }

#pragma unroll
    for (int i = 0; i < 8; ++i) {
        int r = row0 + ty * 4 + (i & 3) + ((i >> 2) << 6);
        if (r >= M) continue;
#pragma unroll
        for (int jj = 0; jj < 2; ++jj) {
            int c = col0 + tx * 4 + jj * 64;
            float v[4] = {acc[i][jj * 4], acc[i][jj * 4 + 1], acc[i][jj * 4 + 2], acc[i][jj * 4 + 3]};
            if constexpr (EPI & EPI_BIAS) {
#pragma unroll
                for (int u = 0; u < 4; ++u) v[u] += bias[c + u];
            }
            if constexpr (EPI & EPI_GELU) {
#pragma unroll
                for (int u = 0; u < 4; ++u) v[u] = gelu_f(v[u]);
            }
            if constexpr (EPI & EPI_PATCH) {
                int pb = r / NPATCH, pt = r % NPATCH;
                size_t o = ((size_t)pb * NTOK + 1 + pt) * DMODEL + c;
                const float* pe = &extra[(size_t)(1 + pt) * DMODEL + c];
                float4 w4 = make_float4(v[0] + pe[0], v[1] + pe[1], v[2] + pe[2], v[3] + pe[3]);
                *(float4*)&C[o] = w4;
            } else if constexpr (EPI & EPI_RESID) {
                size_t o = (size_t)r * N + c;
                const float* rv = &extra[o];
                float4 w4 = make_float4(v[0] + rv[0], v[1] + rv[1], v[2] + rv[2], v[3] + rv[3]);
                *(float4*)&C[o] = w4;
            } else {
                float4 w4 = make_float4(v[0], v[1], v[2], v[3]);
                *(float4*)&C[(size_t)r * N + c] = w4;
            }
        }
    }
}

// ---------------- attention: one wave per q-row, two-pass softmax in LDS ----------------
__global__ __launch_bounds__(256) void attn_k(const float* __restrict__ qkv, float* o, int N) {
    __shared__ float sc[4][208];
    int bh = blockIdx.x;
    int b = bh / NHEAD, h = bh % NHEAD;
    int w = threadIdx.x >> 6, l = threadIdx.x & 63;
    int row = blockIdx.y * 4 + w;
    if (row >= N) return;
    const float* base = qkv + (size_t)b * N * (3 * DMODEL) + h * DHEAD;
    float q = base[(size_t)row * (3 * DMODEL) + l] * 0.125f;  // 1/sqrt(64)
    float m = -1e30f;
    for (int j = 0; j < N; ++j) {
        float s = q * base[(size_t)j * (3 * DMODEL) + DMODEL + l];
        for (int off = 32; off; off >>= 1) s += __shfl_xor(s, off);
        if (l == 0) sc[w][j] = s;
        m = fmaxf(m, s);
    }
    float Z = 0.0f;
    for (int j = l; j < N; j += 64) {
        float p = expf(sc[w][j] - m);
        sc[w][j] = p;
        Z += p;
    }
    for (int off = 32; off; off >>= 1) Z += __shfl_xor(Z, off);
    float inv = 1.0f / Z;
    float acc = 0.0f;
    for (int j = 0; j < N; ++j) acc += sc[w][j] * base[(size_t)j * (3 * DMODEL) + 2 * DMODEL + l];
    o[((size_t)b * N + row) * DMODEL + h * DHEAD + l] = acc * inv;
}

// ---------------- selector score: dot(gelu_out[row,:128], w2) + b2 ----------------
__global__ __launch_bounds__(256) void score_k(const float* __restrict__ gout, const float* __restrict__ w2,
                                               const float* __restrict__ b2, float* scores, int ntok) {
    int w = threadIdx.x >> 6, l = threadIdx.x & 63;
    int row = blockIdx.x * 4 + w;
    if (row >= ntok) return;
    float v = gout[(size_t)row * SELH + l] * w2[l] + gout[(size_t)row * SELH + 64 + l] * w2[64 + l];
    for (int off = 32; off; off >>= 1) v += __shfl_xor(v, off);
    if (l == 0) scores[row] = v + b2[0];
}

// ---------------- top-K (rank-count, deterministic compaction by ascending index) ----------------
__global__ __launch_bounds__(256) void topk_k(const float* __restrict__ scores, int* idx) {
    __shared__ float s[NPATCH];
    __shared__ unsigned char keep[NPATCH];
    int b = blockIdx.x, tid = threadIdx.x;
    if (tid < NPATCH) s[tid] = scores[b * NTOK + 1 + tid];
    if (tid == 0) idx[b * NRED] = 0;  // CLS always slot 0
    __syncthreads();
    if (tid < NPATCH) {
        float v = s[tid];
        int r = 0;
        for (int j = 0; j < NPATCH; ++j) {
            float u = s[j];
            r += (u > v) || (u == v && j < tid);
        }
        keep[tid] = (r < KSEL) ? 1 : 0;
    }
    __syncthreads();
    if (tid < NPATCH && keep[tid]) {
        int p = 1;
        for (int j = 0; j < tid; ++j) p += keep[j];
        idx[b * NRED + p] = tid + 1;
    }
}

// ---------------- gather selected tokens ----------------
__global__ __launch_bounds__(256) void gather_k(const float* __restrict__ x, const int* __restrict__ idx,
                                                float* xr) {
    int i = blockIdx.x * 256 + threadIdx.x;
    const int tot = BATCH * NRED * (DMODEL / 4);
    if (i >= tot) return;
    int d4 = i % (DMODEL / 4), rs = i / (DMODEL / 4);
    int b = rs / NRED, slot = rs % NRED;
    int tok = idx[b * NRED + slot];
    ((float4*)xr)[(size_t)rs * (DMODEL / 4) + d4] =
        ((const float4*)x)[((size_t)b * NTOK + tok) * (DMODEL / 4) + d4];
}

// ---------------- head: out[b,:] = xcls[b,:] @ head_w + head_b ----------------
__global__ __launch_bounds__(64) void head_k(const float* __restrict__ xcls, const float* __restrict__ hw,
                                             const float* __restrict__ hb, float* out) {
    int b = blockIdx.x, l = threadIdx.x;
    const float* xr = xcls + (size_t)b * DMODEL;
    for (int n = 0; n < NCLS; ++n) {
        float v = 0.0f;
        for (int d = l; d < DMODEL; d += 64) v += xr[d] * hw[(size_t)d * NCLS + n];
        for (int off = 32; off; off >>= 1) v += __shfl_xor(v, off);
        if (l == 0) out[b * NCLS + n] = v + hb[n];
    }
}

// ---------------- orchestration ----------------
extern "C" void kernel_launch(void* const* d_in, const int* in_sizes, int n_in,
                              void* d_out, int out_size, void* d_ws, size_t ws_size,
                              hipStream_t stream) {
    const float* x        = (const float*)d_in[0];
    const float* patch_w  = (const float*)d_in[1];
    const float* patch_b  = (const float*)d_in[2];
    const float* cls_tok  = (const float*)d_in[3];
    const float* pos      = (const float*)d_in[4];
    const float* ln1_g    = (const float*)d_in[5];
    const float* ln1_b    = (const float*)d_in[6];
    const float* qkv_w    = (const float*)d_in[7];
    const float* qkv_b    = (const float*)d_in[8];
    const float* proj_w   = (const float*)d_in[9];
    const float* proj_b   = (const float*)d_in[10];
    const float* ln2_g    = (const float*)d_in[11];
    const float* ln2_b    = (const float*)d_in[12];
    const float* fc1_w    = (const float*)d_in[13];
    const float* fc1_b    = (const float*)d_in[14];
    const float* fc2_w    = (const float*)d_in[15];
    const float* fc2_b    = (const float*)d_in[16];
    const float* sel_ln_g = (const float*)d_in[17];
    const float* sel_ln_b = (const float*)d_in[18];
    const float* sel_w1   = (const float*)d_in[19];
    const float* sel_b1   = (const float*)d_in[20];
    const float* sel_w2   = (const float*)d_in[21];
    const float* sel_b2   = (const float*)d_in[22];
    const float* norm_g   = (const float*)d_in[23];
    const float* norm_b   = (const float*)d_in[24];
    const float* head_w   = (const float*)d_in[25];
    const float* head_b   = (const float*)d_in[26];
    float* out = (float*)d_out;

    float* ws = (float*)d_ws;
    const size_t szTok = (size_t)BATCH * NTOK * DMODEL;        // 4,841,472
    float* bufA   = ws;                                        // x tokens [B,197,768]
    float* bufB   = bufA + szTok;                              // h / o scratch
    float* bufC   = bufB + szTok;                              // qkv / mlp / im2col (B*197*3072)
    float* bufXR  = bufC + (size_t)BATCH * NTOK * MLPD;        // selected tokens [B,65,768]
    float* bufW   = bufXR + (size_t)BATCH * NRED * DMODEL;     // transposed patch_w
    float* scores = bufW + (size_t)DMODEL * DMODEL;            // [B*197]
    int*   idxb   = (int*)(scores + BATCH * NTOK);             // [B*65]

    // ---- patch embed ----
    {
        size_t tot = (size_t)BATCH * NPATCH * DMODEL;
        im2col_k<<<dim3((unsigned)((tot + 255) / 256)), 256, 0, stream>>>(x, bufC);
    }
    transpose_k<<<dim3((DMODEL * DMODEL + 255) / 256), 256, 0, stream>>>(patch_w, bufW);
    sgemm_k<EPI_BIAS | EPI_PATCH><<<dim3(DMODEL / GBN, (BATCH * NPATCH) / GBM), 256, 0, stream>>>(
        bufC, bufW, patch_b, pos, bufA, BATCH * NPATCH, DMODEL, DMODEL);
    cls_k<<<dim3((BATCH * DMODEL + 255) / 256), 256, 0, stream>>>(cls_tok, pos, bufA);

    // ---- transformer block ----
    auto run_block = [&](int i, float* X, int N, int M) {
        int mg = (M + GBM - 1) / GBM;
        ln_k<<<M, 256, 0, stream>>>(X, bufB, ln1_g + i * DMODEL, ln1_b + i * DMODEL, DMODEL);
        sgemm_k<EPI_BIAS><<<dim3(3 * DMODEL / GBN, mg), 256, 0, stream>>>(
            bufB, qkv_w + (size_t)i * DMODEL * 3 * DMODEL, qkv_b + i * 3 * DMODEL, nullptr, bufC,
            M, 3 * DMODEL, DMODEL);
        attn_k<<<dim3(BATCH * NHEAD, (N + 3) / 4), 256, 0, stream>>>(bufC, bufB, N);
        sgemm_k<EPI_BIAS | EPI_RESID><<<dim3(DMODEL / GBN, mg), 256, 0, stream>>>(
            bufB, proj_w + (size_t)i * DMODEL * DMODEL, proj_b + i * DMODEL, X, X, M, DMODEL, DMODEL);
        ln_k<<<M, 256, 0, stream>>>(X, bufB, ln2_g + i * DMODEL, ln2_b + i * DMODEL, DMODEL);
        sgemm_k<EPI_BIAS | EPI_GELU><<<dim3(MLPD / GBN, mg), 256, 0, stream>>>(
            bufB, fc1_w + (size_t)i * DMODEL * MLPD, fc1_b + i * MLPD, nullptr, bufC, M, MLPD, DMODEL);
        sgemm_k<EPI_BIAS | EPI_RESID><<<dim3(DMODEL / GBN, mg), 256, 0, stream>>>(
            bufC, fc2_w + (size_t)i * MLPD * DMODEL, fc2_b + i * DMODEL, X, X, M, DMODEL, MLPD);
    };

    for (int i = 0; i < WARM; ++i) run_block(i, bufA, NTOK, BATCH * NTOK);

    // ---- token selector ----
    ln_k<<<BATCH * NTOK, 256, 0, stream>>>(bufA, bufB, sel_ln_g, sel_ln_b, DMODEL);
    sgemm_k<EPI_BIAS | EPI_GELU><<<dim3(SELH / GBN, (BATCH * NTOK + GBM - 1) / GBM), 256, 0, stream>>>(
        bufB, sel_w1, sel_b1, nullptr, bufC, BATCH * NTOK, SELH, DMODEL);
    score_k<<<dim3((BATCH * NTOK + 3) / 4), 256, 0, stream>>>(bufC, sel_w2, sel_b2, scores, BATCH * NTOK);
    topk_k<<<BATCH, 256, 0, stream>>>(scores, idxb);
    gather_k<<<dim3((BATCH * NRED * (DMODEL / 4) + 255) / 256), 256, 0, stream>>>(bufA, idxb, bufXR);

    for (int i = WARM; i < DEPTH; ++i) run_block(i, bufXR, NRED, BATCH * NRED);

    // ---- final LN on CLS rows + head ----
    ln_k<<<BATCH, 256, 0, stream>>>(bufXR, bufB, norm_g, norm_b, (size_t)NRED * DMODEL);
    head_k<<<BATCH, 64, 0, stream>>>(bufB, head_w, head_b, out);
}

// Round 4
// 11383.604 us; speedup vs baseline: 1.4340x; 1.4340x over previous
//
#include <hip/hip_runtime.h>
#include <hip/hip_bf16.h>
#include <math.h>

// ---------------- problem constants ----------------
#define BATCH 32
#define DMODEL 768
#define NHEAD 12
#define DHEAD 64
#define DEPTH 12
#define WARM 2
#define KSEL 64
#define MLPD 3072
#define SELH 128
#define NCLS 10
#define PATCH 16
#define IMG 224
#define NTOK 197          // 196 patches + cls
#define NPATCH 196
#define NRED 65           // 1 + K selected tokens
#define LNEPS 1e-6f

// ---------------- helpers ----------------
__device__ __forceinline__ float gelu_f(float x) {
    return 0.5f * x * (1.0f + erff(x * 0.70710678118654752f));
}

// ---------------- im2col (stride-16 / kernel-16 patches: pure re-index) ----------------
__global__ __launch_bounds__(256) void im2col_k(const float* __restrict__ x, float* __restrict__ out) {
    size_t i = (size_t)blockIdx.x * 256 + threadIdx.x;
    const size_t tot = (size_t)BATCH * NPATCH * DMODEL;
    if (i >= tot) return;
    int k = (int)(i % DMODEL);
    int m = (int)(i / DMODEL);
    int b = m / NPATCH, t = m % NPATCH;
    int py = t / 14, px = t % 14;
    int c = k / 256, r = k % 256;
    int kh = r / 16, kw = r % 16;
    out[i] = x[(((size_t)b * 3 + c) * IMG + py * 16 + kh) * IMG + px * 16 + kw];
}

// ---------------- transpose patch_w [D,768] -> [768,D] ----------------
__global__ __launch_bounds__(256) void transpose_k(const float* __restrict__ w, float* wt) {
    int i = blockIdx.x * 256 + threadIdx.x;
    if (i < DMODEL * DMODEL) {
        int d = i / DMODEL, k = i % DMODEL;
        wt[(size_t)k * DMODEL + d] = w[i];
    }
}

// ---------------- cls row: cls_token + pos_embed[0] ----------------
__global__ __launch_bounds__(256) void cls_k(const float* __restrict__ cls_tok, const float* __restrict__ pos,
                                             float* xtok) {
    int i = blockIdx.x * 256 + threadIdx.x;
    if (i < BATCH * DMODEL) {
        int b = i / DMODEL, d = i % DMODEL;
        xtok[(size_t)b * NTOK * DMODEL + d] = cls_tok[d] + pos[d];
    }
}

// ---------------- LayerNorm: one 256-thread block per row (768 cols) ----------------
__global__ __launch_bounds__(256) void ln_k(const float* __restrict__ in, float* out,
                                            const float* __restrict__ g, const float* __restrict__ b,
                                            size_t rstride) {
    int row = blockIdx.x;
    const float* p = in + (size_t)row * rstride;
    int tid = threadIdx.x;
    float v0 = p[tid], v1 = p[tid + 256], v2 = p[tid + 512];
    float s = v0 + v1 + v2;
    float sq = v0 * v0 + v1 * v1 + v2 * v2;
    for (int off = 32; off; off >>= 1) {
        s += __shfl_xor(s, off);
        sq += __shfl_xor(sq, off);
    }
    __shared__ float red[8];
    int wid = tid >> 6;
    if ((tid & 63) == 0) { red[wid] = s; red[wid + 4] = sq; }
    __syncthreads();
    s = red[0] + red[1] + red[2] + red[3];
    sq = red[4] + red[5] + red[6] + red[7];
    float mean = s * (1.0f / 768.0f);
    float var = sq * (1.0f / 768.0f) - mean * mean;
    float inv = 1.0f / sqrtf(var + LNEPS);
    float* q = out + (size_t)row * DMODEL;
    q[tid]       = (v0 - mean) * inv * g[tid]       + b[tid];
    q[tid + 256] = (v1 - mean) * inv * g[tid + 256] + b[tid + 256];
    q[tid + 512] = (v2 - mean) * inv * g[tid + 512] + b[tid + 512];
}

// ---------------- GEMM v2: C[M,N] = A[M,K] @ W[K,N] (+epilogues) ----------------
// BK=16, double-buffered LDS, register-prefetch pipeline, one barrier per K-tile.
// BM=BN=128: 256 thr, 8x8 micro.  BM=BN=64: 256 thr, 4x4 micro (for small-N GEMMs).
constexpr int EPI_BIAS = 1, EPI_GELU = 2, EPI_RESID = 4, EPI_PATCH = 8;

template <int BM, int BN, int EPI>
__global__ __launch_bounds__(256) void gemm2_k(const float* __restrict__ A, const float* __restrict__ W,
                                               const float* __restrict__ bias, const float* __restrict__ extra,
                                               float* __restrict__ C, int M, int N, int K) {
    constexpr int BK = 16;
    constexpr int RS = BM / 64;              // row splits (2 or 1)
    constexpr int CS = BN / 64;              // col splits
    constexpr int AF = (BM * BK) / (256 * 4);  // float4 A-loads per thread
    constexpr int BF = (BN * BK) / (256 * 4);
    __shared__ float As[2][BK][BM];
    __shared__ float Bs[2][BK][BN];

    const int tid = threadIdx.x;
    const int tx = tid & 15, ty = tid >> 4;
    const int row0 = blockIdx.y * BM, col0 = blockIdx.x * BN;

    int arow[AF], acol[AF];
    bool aok[AF];
    const float* aptr[AF];
#pragma unroll
    for (int f = 0; f < AF; ++f) {
        int idx = tid + f * 256;             // < BM*4
        arow[f] = idx >> 2;
        acol[f] = (idx & 3) << 2;
        aok[f] = (row0 + arow[f]) < M;
        aptr[f] = A + (size_t)(row0 + arow[f]) * K + acol[f];
    }
    int brow[BF], bcol[BF];
    const float* bptr[BF];
#pragma unroll
    for (int f = 0; f < BF; ++f) {
        int idx = tid + f * 256;             // < BN*4
        brow[f] = idx / (BN / 4);
        bcol[f] = (idx % (BN / 4)) << 2;
        bptr[f] = W + (size_t)brow[f] * N + col0 + bcol[f];
    }

    float4 aR[AF], bR[BF];
    // prologue: tile 0 -> LDS buf 0
#pragma unroll
    for (int f = 0; f < AF; ++f) aR[f] = aok[f] ? *(const float4*)aptr[f] : make_float4(0.f, 0.f, 0.f, 0.f);
#pragma unroll
    for (int f = 0; f < BF; ++f) bR[f] = *(const float4*)bptr[f];
#pragma unroll
    for (int f = 0; f < AF; ++f) {
        As[0][acol[f] + 0][arow[f]] = aR[f].x;
        As[0][acol[f] + 1][arow[f]] = aR[f].y;
        As[0][acol[f] + 2][arow[f]] = aR[f].z;
        As[0][acol[f] + 3][arow[f]] = aR[f].w;
    }
#pragma unroll
    for (int f = 0; f < BF; ++f) *(float4*)&Bs[0][brow[f]][bcol[f]] = bR[f];
    __syncthreads();

    float acc[RS * 4][CS * 4];
#pragma unroll
    for (int i = 0; i < RS * 4; ++i)
#pragma unroll
        for (int j = 0; j < CS * 4; ++j) acc[i][j] = 0.f;

    auto compute = [&](int buf) {
#pragma unroll
        for (int k = 0; k < BK; ++k) {
            float ar[RS * 4], br[CS * 4];
#pragma unroll
            for (int s = 0; s < RS; ++s) *(float4*)&ar[s * 4] = *(const float4*)&As[buf][k][s * 64 + ty * 4];
#pragma unroll
            for (int s = 0; s < CS; ++s) *(float4*)&br[s * 4] = *(const float4*)&Bs[buf][k][s * 64 + tx * 4];
#pragma unroll
            for (int i = 0; i < RS * 4; ++i)
#pragma unroll
                for (int j = 0; j < CS * 4; ++j) acc[i][j] = fmaf(ar[i], br[j], acc[i][j]);
        }
    };

    const int nk = K / BK;
    int p = 0;
    for (int kk = 1; kk < nk; ++kk) {
        // issue next tile's global loads (in flight during compute)
#pragma unroll
        for (int f = 0; f < AF; ++f) {
            aptr[f] += BK;
            aR[f] = aok[f] ? *(const float4*)aptr[f] : make_float4(0.f, 0.f, 0.f, 0.f);
        }
#pragma unroll
        for (int f = 0; f < BF; ++f) {
            bptr[f] += (size_t)BK * N;
            bR[f] = *(const float4*)bptr[f];
        }
        compute(p);
        int q = p ^ 1;
#pragma unroll
        for (int f = 0; f < AF; ++f) {
            As[q][acol[f] + 0][arow[f]] = aR[f].x;
            As[q][acol[f] + 1][arow[f]] = aR[f].y;
            As[q][acol[f] + 2][arow[f]] = aR[f].z;
            As[q][acol[f] + 3][arow[f]] = aR[f].w;
        }
#pragma unroll
        for (int f = 0; f < BF; ++f) *(float4*)&Bs[q][brow[f]][bcol[f]] = bR[f];
        __syncthreads();
        p = q;
    }
    compute(p);

    // epilogue
#pragma unroll
    for (int i = 0; i < RS * 4; ++i) {
        int r = row0 + (i >> 2) * 64 + ty * 4 + (i & 3);
        if (r >= M) continue;
#pragma unroll
        for (int t = 0; t < CS; ++t) {
            int c = col0 + t * 64 + tx * 4;
            float v[4] = {acc[i][t * 4], acc[i][t * 4 + 1], acc[i][t * 4 + 2], acc[i][t * 4 + 3]};
            if constexpr (EPI & EPI_BIAS) {
#pragma unroll
                for (int u = 0; u < 4; ++u) v[u] += bias[c + u];
            }
            if constexpr (EPI & EPI_GELU) {
#pragma unroll
                for (int u = 0; u < 4; ++u) v[u] = gelu_f(v[u]);
            }
            if constexpr (EPI & EPI_PATCH) {
                int pb = r / NPATCH, pt = r % NPATCH;
                size_t o = ((size_t)pb * NTOK + 1 + pt) * DMODEL + c;
                const float* pe = &extra[(size_t)(1 + pt) * DMODEL + c];
                float4 w4 = make_float4(v[0] + pe[0], v[1] + pe[1], v[2] + pe[2], v[3] + pe[3]);
                *(float4*)&C[o] = w4;
            } else if constexpr (EPI & EPI_RESID) {
                size_t o = (size_t)r * N + c;
                const float* rv = &extra[o];
                float4 w4 = make_float4(v[0] + rv[0], v[1] + rv[1], v[2] + rv[2], v[3] + rv[3]);
                *(float4*)&C[o] = w4;
            } else {
                *(float4*)&C[(size_t)r * N + c] = make_float4(v[0], v[1], v[2], v[3]);
            }
        }
    }
}

// ---------------- attention v2 ----------------
// One block (256 thr = 4 waves) per (b,h). K staged in LDS (pad-65 stride, conflict-free).
// Each wave batches 4 q-rows; lane l owns keys {l, 64+l, ...}; softmax = one wave-reduce
// per row; P transposed via LDS sc[j][4]; PV reads V from global (coalesced, L2-resident).
template <int N>
__global__ __launch_bounds__(256) void attn2_k(const float* __restrict__ qkv, float* __restrict__ o) {
    constexpr int NG = (N + 63) / 64;
    constexpr int SK = 65;                   // padded K row stride (floats)
    constexpr int SCS = (N + 3) & ~3;        // score rows (>=64, mult of 4)
    __shared__ float Ks[N * SK];
    __shared__ float sc[4][SCS][4];
    const int b = blockIdx.x / NHEAD, h = blockIdx.x % NHEAD;
    const float* base = qkv + (size_t)b * N * (3 * DMODEL) + h * DHEAD;

    // stage K
    for (int idx = threadIdx.x; idx < N * 16; idx += 256) {
        int r = idx >> 4, c = (idx & 15) << 2;
        float4 kv = *(const float4*)(base + (size_t)r * (3 * DMODEL) + DMODEL + c);
        float* d = &Ks[r * SK + c];
        d[0] = kv.x; d[1] = kv.y; d[2] = kv.z; d[3] = kv.w;
    }
    __syncthreads();

    const int w = threadIdx.x >> 6, l = threadIdx.x & 63;
    const float* Vbase = base + 2 * DMODEL + l;

    for (int r0 = w * 4; r0 < N; r0 += 16) {
        // load 4 q values (lane l holds dim l of each row), stage to sc[w][l][0..3]
        {
            float q0, q1, q2, q3;
            int ra = r0, rb = min(r0 + 1, N - 1), rc = min(r0 + 2, N - 1), rd = min(r0 + 3, N - 1);
            q0 = base[(size_t)ra * (3 * DMODEL) + l] * 0.125f;
            q1 = base[(size_t)rb * (3 * DMODEL) + l] * 0.125f;
            q2 = base[(size_t)rc * (3 * DMODEL) + l] * 0.125f;
            q3 = base[(size_t)rd * (3 * DMODEL) + l] * 0.125f;
            *(float4*)&sc[w][l][0] = make_float4(q0, q1, q2, q3);
        }
        // QK^T: s[row][g] = dot(q_row, k_{g*64+l})
        float s[4][NG];
#pragma unroll
        for (int i = 0; i < 4; ++i)
#pragma unroll
            for (int g = 0; g < NG; ++g) s[i][g] = 0.f;
#pragma unroll 4
        for (int d = 0; d < 64; ++d) {
            float4 qd = *(const float4*)&sc[w][d][0];   // broadcast: q[d] of the 4 rows
#pragma unroll
            for (int g = 0; g < NG; ++g) {
                int j = g * 64 + l;
                int jr = j < N ? j : N - 1;
                float kv = Ks[jr * SK + d];
                s[0][g] = fmaf(qd.x, kv, s[0][g]);
                s[1][g] = fmaf(qd.y, kv, s[1][g]);
                s[2][g] = fmaf(qd.z, kv, s[2][g]);
                s[3][g] = fmaf(qd.w, kv, s[3][g]);
            }
        }
        // mask invalid keys, per-row max
        float m[4], Z[4], pv[4][NG];
#pragma unroll
        for (int i = 0; i < 4; ++i) {
            float mm = -3e38f;
#pragma unroll
            for (int g = 0; g < NG; ++g) {
                if (g * 64 + l >= N) s[i][g] = -3e38f;
                mm = fmaxf(mm, s[i][g]);
            }
            m[i] = mm;
        }
#pragma unroll
        for (int off = 32; off; off >>= 1) {
#pragma unroll
            for (int i = 0; i < 4; ++i) m[i] = fmaxf(m[i], __shfl_xor(m[i], off));
        }
#pragma unroll
        for (int i = 0; i < 4; ++i) {
            float zz = 0.f;
#pragma unroll
            for (int g = 0; g < NG; ++g) { pv[i][g] = expf(s[i][g] - m[i]); zz += pv[i][g]; }
            Z[i] = zz;
        }
#pragma unroll
        for (int off = 32; off; off >>= 1) {
#pragma unroll
            for (int i = 0; i < 4; ++i) Z[i] += __shfl_xor(Z[i], off);
        }
        // transpose P into LDS: sc[w][j][row]  (overwrites q staging)
#pragma unroll
        for (int g = 0; g < NG; ++g) {
            int j = g * 64 + l;
            if (j < N) *(float4*)&sc[w][j][0] = make_float4(pv[0][g], pv[1][g], pv[2][g], pv[3][g]);
        }
        // PV: lane l = output dim l; V read coalesced from global
        float acc0 = 0.f, acc1 = 0.f, acc2 = 0.f, acc3 = 0.f;
#pragma unroll 8
        for (int j = 0; j < N; ++j) {
            float4 pj = *(const float4*)&sc[w][j][0];   // broadcast
            float vv = Vbase[(size_t)j * (3 * DMODEL)];
            acc0 = fmaf(pj.x, vv, acc0);
            acc1 = fmaf(pj.y, vv, acc1);
            acc2 = fmaf(pj.z, vv, acc2);
            acc3 = fmaf(pj.w, vv, acc3);
        }
        float accs[4] = {acc0, acc1, acc2, acc3};
#pragma unroll
        for (int i = 0; i < 4; ++i) {
            int rr = r0 + i;
            if (rr < N) o[((size_t)b * N + rr) * DMODEL + h * DHEAD + l] = accs[i] / Z[i];
        }
    }
}

// ---------------- selector score: dot(gelu_out[row,:128], w2) + b2 ----------------
__global__ __launch_bounds__(256) void score_k(const float* __restrict__ gout, const float* __restrict__ w2,
                                               const float* __restrict__ b2, float* scores, int ntok) {
    int w = threadIdx.x >> 6, l = threadIdx.x & 63;
    int row = blockIdx.x * 4 + w;
    if (row >= ntok) return;
    float v = gout[(size_t)row * SELH + l] * w2[l] + gout[(size_t)row * SELH + 64 + l] * w2[64 + l];
    for (int off = 32; off; off >>= 1) v += __shfl_xor(v, off);
    if (l == 0) scores[row] = v + b2[0];
}

// ---------------- top-K (rank-count, deterministic compaction by ascending index) ----------------
__global__ __launch_bounds__(256) void topk_k(const float* __restrict__ scores, int* idx) {
    __shared__ float s[NPATCH];
    __shared__ unsigned char keep[NPATCH];
    int b = blockIdx.x, tid = threadIdx.x;
    if (tid < NPATCH) s[tid] = scores[b * NTOK + 1 + tid];
    if (tid == 0) idx[b * NRED] = 0;  // CLS always slot 0
    __syncthreads();
    if (tid < NPATCH) {
        float v = s[tid];
        int r = 0;
        for (int j = 0; j < NPATCH; ++j) {
            float u = s[j];
            r += (u > v) || (u == v && j < tid);
        }
        keep[tid] = (r < KSEL) ? 1 : 0;
    }
    __syncthreads();
    if (tid < NPATCH && keep[tid]) {
        int p = 1;
        for (int j = 0; j < tid; ++j) p += keep[j];
        idx[b * NRED + p] = tid + 1;
    }
}

// ---------------- gather selected tokens ----------------
__global__ __launch_bounds__(256) void gather_k(const float* __restrict__ x, const int* __restrict__ idx,
                                                float* xr) {
    int i = blockIdx.x * 256 + threadIdx.x;
    const int tot = BATCH * NRED * (DMODEL / 4);
    if (i >= tot) return;
    int d4 = i % (DMODEL / 4), rs = i / (DMODEL / 4);
    int b = rs / NRED, slot = rs % NRED;
    int tok = idx[b * NRED + slot];
    ((float4*)xr)[(size_t)rs * (DMODEL / 4) + d4] =
        ((const float4*)x)[((size_t)b * NTOK + tok) * (DMODEL / 4) + d4];
}

// ---------------- head: out[b,:] = xcls[b,:] @ head_w + head_b ----------------
__global__ __launch_bounds__(64) void head_k(const float* __restrict__ xcls, const float* __restrict__ hw,
                                             const float* __restrict__ hb, float* out) {
    int b = blockIdx.x, l = threadIdx.x;
    const float* xr = xcls + (size_t)b * DMODEL;
    for (int n = 0; n < NCLS; ++n) {
        float v = 0.0f;
        for (int d = l; d < DMODEL; d += 64) v += xr[d] * hw[(size_t)d * NCLS + n];
        for (int off = 32; off; off >>= 1) v += __shfl_xor(v, off);
        if (l == 0) out[b * NCLS + n] = v + hb[n];
    }
}

// ---------------- orchestration ----------------
extern "C" void kernel_launch(void* const* d_in, const int* in_sizes, int n_in,
                              void* d_out, int out_size, void* d_ws, size_t ws_size,
                              hipStream_t stream) {
    const float* x        = (const float*)d_in[0];
    const float* patch_w  = (const float*)d_in[1];
    const float* patch_b  = (const float*)d_in[2];
    const float* cls_tok  = (const float*)d_in[3];
    const float* pos      = (const float*)d_in[4];
    const float* ln1_g    = (const float*)d_in[5];
    const float* ln1_b    = (const float*)d_in[6];
    const float* qkv_w    = (const float*)d_in[7];
    const float* qkv_b    = (const float*)d_in[8];
    const float* proj_w   = (const float*)d_in[9];
    const float* proj_b   = (const float*)d_in[10];
    const float* ln2_g    = (const float*)d_in[11];
    const float* ln2_b    = (const float*)d_in[12];
    const float* fc1_w    = (const float*)d_in[13];
    const float* fc1_b    = (const float*)d_in[14];
    const float* fc2_w    = (const float*)d_in[15];
    const float* fc2_b    = (const float*)d_in[16];
    const float* sel_ln_g = (const float*)d_in[17];
    const float* sel_ln_b = (const float*)d_in[18];
    const float* sel_w1   = (const float*)d_in[19];
    const float* sel_b1   = (const float*)d_in[20];
    const float* sel_w2   = (const float*)d_in[21];
    const float* sel_b2   = (const float*)d_in[22];
    const float* norm_g   = (const float*)d_in[23];
    const float* norm_b   = (const float*)d_in[24];
    const float* head_w   = (const float*)d_in[25];
    const float* head_b   = (const float*)d_in[26];
    float* out = (float*)d_out;

    float* ws = (float*)d_ws;
    const size_t szTok = (size_t)BATCH * NTOK * DMODEL;
    float* bufA   = ws;                                        // x tokens [B,197,768]
    float* bufB   = bufA + szTok;                              // h / o scratch
    float* bufC   = bufB + szTok;                              // qkv / mlp / im2col
    float* bufXR  = bufC + (size_t)BATCH * NTOK * MLPD;        // selected tokens [B,65,768]
    float* bufW   = bufXR + (size_t)BATCH * NRED * DMODEL;     // transposed patch_w
    float* scores = bufW + (size_t)DMODEL * DMODEL;
    int*   idxb   = (int*)(scores + BATCH * NTOK);

    // ---- patch embed ----
    {
        size_t tot = (size_t)BATCH * NPATCH * DMODEL;
        im2col_k<<<dim3((unsigned)((tot + 255) / 256)), 256, 0, stream>>>(x, bufC);
    }
    transpose_k<<<dim3((DMODEL * DMODEL + 255) / 256), 256, 0, stream>>>(patch_w, bufW);
    gemm2_k<128, 128, EPI_BIAS | EPI_PATCH><<<dim3(DMODEL / 128, (BATCH * NPATCH) / 128), 256, 0, stream>>>(
        bufC, bufW, patch_b, pos, bufA, BATCH * NPATCH, DMODEL, DMODEL);
    cls_k<<<dim3((BATCH * DMODEL + 255) / 256), 256, 0, stream>>>(cls_tok, pos, bufA);

    // ---- transformer block ----
    auto run_block = [&](int i, float* X, int N, int M, bool small) {
        int mg128 = (M + 127) / 128;
        int mg64 = (M + 63) / 64;
        ln_k<<<M, 256, 0, stream>>>(X, bufB, ln1_g + i * DMODEL, ln1_b + i * DMODEL, DMODEL);
        gemm2_k<128, 128, EPI_BIAS><<<dim3(3 * DMODEL / 128, mg128), 256, 0, stream>>>(
            bufB, qkv_w + (size_t)i * DMODEL * 3 * DMODEL, qkv_b + i * 3 * DMODEL, nullptr, bufC,
            M, 3 * DMODEL, DMODEL);
        if (N == NTOK)
            attn2_k<NTOK><<<dim3(BATCH * NHEAD), 256, 0, stream>>>(bufC, bufB);
        else
            attn2_k<NRED><<<dim3(BATCH * NHEAD), 256, 0, stream>>>(bufC, bufB);
        if (small) {
            gemm2_k<64, 64, EPI_BIAS | EPI_RESID><<<dim3(DMODEL / 64, mg64), 256, 0, stream>>>(
                bufB, proj_w + (size_t)i * DMODEL * DMODEL, proj_b + i * DMODEL, X, X, M, DMODEL, DMODEL);
        } else {
            gemm2_k<128, 128, EPI_BIAS | EPI_RESID><<<dim3(DMODEL / 128, mg128), 256, 0, stream>>>(
                bufB, proj_w + (size_t)i * DMODEL * DMODEL, proj_b + i * DMODEL, X, X, M, DMODEL, DMODEL);
        }
        ln_k<<<M, 256, 0, stream>>>(X, bufB, ln2_g + i * DMODEL, ln2_b + i * DMODEL, DMODEL);
        gemm2_k<128, 128, EPI_BIAS | EPI_GELU><<<dim3(MLPD / 128, mg128), 256, 0, stream>>>(
            bufB, fc1_w + (size_t)i * DMODEL * MLPD, fc1_b + i * MLPD, nullptr, bufC, M, MLPD, DMODEL);
        if (small) {
            gemm2_k<64, 64, EPI_BIAS | EPI_RESID><<<dim3(DMODEL / 64, mg64), 256, 0, stream>>>(
                bufC, fc2_w + (size_t)i * MLPD * DMODEL, fc2_b + i * DMODEL, X, X, M, DMODEL, MLPD);
        } else {
            gemm2_k<128, 128, EPI_BIAS | EPI_RESID><<<dim3(DMODEL / 128, mg128), 256, 0, stream>>>(
                bufC, fc2_w + (size_t)i * MLPD * DMODEL, fc2_b + i * DMODEL, X, X, M, DMODEL, MLPD);
        }
    };

    for (int i = 0; i < WARM; ++i) run_block(i, bufA, NTOK, BATCH * NTOK, false);

    // ---- token selector ----
    ln_k<<<BATCH * NTOK, 256, 0, stream>>>(bufA, bufB, sel_ln_g, sel_ln_b, DMODEL);
    gemm2_k<64, 64, EPI_BIAS | EPI_GELU><<<dim3(SELH / 64, (BATCH * NTOK + 63) / 64), 256, 0, stream>>>(
        bufB, sel_w1, sel_b1, nullptr, bufC, BATCH * NTOK, SELH, DMODEL);
    score_k<<<dim3((BATCH * NTOK + 3) / 4), 256, 0, stream>>>(bufC, sel_w2, sel_b2, scores, BATCH * NTOK);
    topk_k<<<BATCH, 256, 0, stream>>>(scores, idxb);
    gather_k<<<dim3((BATCH * NRED * (DMODEL / 4) + 255) / 256), 256, 0, stream>>>(bufA, idxb, bufXR);

    for (int i = WARM; i < DEPTH; ++i) run_block(i, bufXR, NRED, BATCH * NRED, true);

    // ---- final LN on CLS rows + head ----
    ln_k<<<BATCH, 256, 0, stream>>>(bufXR, bufB, norm_g, norm_b, (size_t)NRED * DMODEL);
    head_k<<<BATCH, 64, 0, stream>>>(bufB, head_w, head_b, out);
}